// Round 2
// 33388.788 us; speedup vs baseline: 1.2745x; 1.2745x over previous
//
#include <hip/hip_runtime.h>
#include <stdint.h>
#include <math.h>

#define BB   8
#define TT   512
#define VV   32000
#define EE   512
#define HH   1024
#define G3H  3072

// ---- workspace layout (byte offsets) ----
#define GX0_OFF 0ULL                 // [B][T][3H] f32 = 50,331,648 B
#define H1_OFF  50331648ULL          // [2][B][H]  f32 = 65,536 B
#define H2_OFF  50397184ULL          // [B][T][H]  f32 = 16,777,216 B
#define BAR_OFF 67174400ULL          // barrier counters
#define XD_OFF  67174656ULL          // decoded indices, 4096 int32

#define NBLK2 256                    // one block per CU; co-residency guaranteed

// ---------------------------------------------------------------- K0: init
__global__ __launch_bounds__(1024) void k_init(const int* __restrict__ xin,
                                               int* __restrict__ xd,
                                               float* __restrict__ h1buf,
                                               unsigned* __restrict__ bar) {
    __shared__ int accum;
    const int tid = threadIdx.x;
    if (tid == 0) accum = 0;
    __syncthreads();
    int v = 0;
    for (int i = tid; i < 2048; i += 1024) v |= xin[2 * i + 1];
    atomicOr(&accum, v);
    __syncthreads();
    const bool is64 = (accum == 0);
    for (int i = tid; i < BB * TT; i += 1024) xd[i] = is64 ? xin[2 * i] : xin[i];
    for (int i = tid; i < 2 * BB * HH; i += 1024) h1buf[i] = 0.f;
    if (tid < 32) bar[tid] = 0u;
}

// ------------------------------------------------- K1: embed + gx0 GEMM
__global__ __launch_bounds__(256) void k_gx0(const float* __restrict__ emb,
                                             const float* __restrict__ w_ih0,
                                             const float* __restrict__ b_ih0,
                                             const int* __restrict__ xd,
                                             float* __restrict__ gx0) {
    __shared__ float As[16][68];
    __shared__ float Bs[16][68];
    const int tid = threadIdx.x;
    const int tx = tid & 15, ty = tid >> 4;
    const int n0 = blockIdx.x * 64;   // gate dim (3072)
    const int m0 = blockIdx.y * 64;   // bt dim (4096)
    const int lrow = tid >> 2;        // 0..63
    const int lk   = (tid & 3) * 4;   // 0,4,8,12
    const int arow = xd[m0 + lrow];
    const float* aptr = emb   + (size_t)arow * EE + lk;
    const float* bptr = w_ih0 + (size_t)(n0 + lrow) * EE + lk;

    float acc[4][4] = {};
    const int rbase = ty * 4, cbase = tx * 4;

    for (int k0 = 0; k0 < EE; k0 += 16) {
        const float4 a4 = *(const float4*)(aptr + k0);
        const float4 b4 = *(const float4*)(bptr + k0);
        As[lk + 0][lrow] = a4.x; As[lk + 1][lrow] = a4.y;
        As[lk + 2][lrow] = a4.z; As[lk + 3][lrow] = a4.w;
        Bs[lk + 0][lrow] = b4.x; Bs[lk + 1][lrow] = b4.y;
        Bs[lk + 2][lrow] = b4.z; Bs[lk + 3][lrow] = b4.w;
        __syncthreads();
#pragma unroll
        for (int k = 0; k < 16; ++k) {
            const float4 av = *(const float4*)&As[k][rbase];
            const float4 bv = *(const float4*)&Bs[k][cbase];
            const float a[4] = {av.x, av.y, av.z, av.w};
            const float b[4] = {bv.x, bv.y, bv.z, bv.w};
#pragma unroll
            for (int i = 0; i < 4; ++i)
#pragma unroll
                for (int j = 0; j < 4; ++j)
                    acc[i][j] = fmaf(a[i], b[j], acc[i][j]);
        }
        __syncthreads();
    }
#pragma unroll
    for (int i = 0; i < 4; ++i) {
        const int r = m0 + rbase + i;
#pragma unroll
        for (int j = 0; j < 4; ++j) {
            const int c = n0 + cbase + j;
            gx0[(size_t)r * G3H + c] = acc[i][j] + b_ih0[c];
        }
    }
}

// ------------------------------------------------- K2: persistent fused GRU
__device__ __forceinline__ float sigmf(float x) { return 1.f / (1.f + expf(-x)); }

// LDS word swizzle: XOR word bits[4:2] with bits[7:5]. Bijective involution
// within each 8192-word half; preserves float4 alignment (bits[1:0] fixed).
// Spreads the stride-64B ds_read_b128 pattern across all 8 bank-quads.
__device__ __forceinline__ int swz(int w) { return w ^ (((w >> 5) & 7) << 2); }

__global__ __launch_bounds__(256, 1) void k_gru(const float* __restrict__ gx0,
                                                const float* __restrict__ w_hh0,
                                                const float* __restrict__ b_hh0,
                                                const float* __restrict__ w_ih1,
                                                const float* __restrict__ b_ih1,
                                                const float* __restrict__ w_hh1,
                                                const float* __restrict__ b_hh1,
                                                float* __restrict__ h1buf,
                                                float* __restrict__ h2seq,
                                                unsigned* __restrict__ bar) {
    const int bid = blockIdx.x;
    const int tid = threadIdx.x;
    const int wv  = tid >> 6;
    const int ln  = tid & 63;
    const int c0  = bid * 4;          // this block's four columns (both layers)

    // Exactly 64 KB: [0,8192) h1[it-1] (swizzled), [8192,16384) h2[it-2].
    // ghb aliases the first 288 words; written only after all hs reads
    // complete (extra __syncthreads), read before next staging (grid barrier).
    __shared__ float hs[16384];
    float* ghb = hs;                  // [36][8] gate-dot results

    // Rows: 0-11 = L0 gh (w_hh0), 12-23 = L1 gx (w_ih1), 24-35 = L1 gh (w_hh1)
    // row i: grp=i/12, rem=i%12, cl=rem/3, gate=rem%3, wrow=gate*HH+c0+cl.
    // Wave w owns rows [9w, 9w+9). Rows using h1 (x1): w0=9, w1=9, w2=6, w3=0.
    const int r0  = wv * 9;
    const int n1v = (wv < 2) ? 9 : (wv == 2) ? 6 : 0;
    const int n1  = __builtin_amdgcn_readfirstlane(n1v);

    // ---- preload weights into registers (once): lane ln owns k in
    //      [16*ln, 16*ln+16) of each of its wave's 9 rows (144 VGPR).
    //      Bias folded into the dot: lane 0 seeds the partial sum.
    float4 wr[9][4];
    float  breg[9];
#pragma unroll
    for (int r = 0; r < 9; ++r) {
        const int i = r0 + r;
        const int grp = i / 12, rem = i % 12;
        const int cl = rem / 3, gate = rem % 3;
        const float* W  = (grp == 0) ? w_hh0 : (grp == 1) ? w_ih1 : w_hh1;
        const float* Bv = (grp == 0) ? b_hh0 : (grp == 1) ? b_ih1 : b_hh1;
        const int wrow = gate * HH + c0 + cl;
        const float* wp = W + (size_t)wrow * HH + ln * 16;
        wr[r][0] = *(const float4*)(wp);
        wr[r][1] = *(const float4*)(wp + 4);
        wr[r][2] = *(const float4*)(wp + 8);
        wr[r][3] = *(const float4*)(wp + 12);
        breg[r] = (ln == 0) ? Bv[wrow] : 0.f;
    }

    float hreg = 0.f;                 // per-thread h recurrence (gate lanes)

    for (int it = 0; it <= TT; ++it) {
        // ---- gx0 prefetch for layer-0 gates (threads 0..31); consumed at
        //      the gate phase — L3 latency hides under staging + dot.
        float xr = 0.f, xz = 0.f, xn = 0.f;
        if (tid < 32 && it < TT) {
            const int b2 = tid >> 2, cl = tid & 3, c = c0 + cl;
            const size_t gb = ((size_t)b2 * TT + it) * G3H;
            xr = gx0[gb + c]; xz = gx0[gb + HH + c]; xn = gx0[gb + 2 * HH + c];
        }

        // ---- stage h1[it-1] and h2[it-2] into swizzled LDS
        const float* h1p = h1buf + ((it + 1) & 1) * (BB * HH);
#pragma unroll
        for (int u = tid; u < 2048; u += 256)
            *(float4*)(hs + swz(u * 4)) = *(const float4*)(h1p + u * 4);
        if (it >= 2) {
#pragma unroll
            for (int u = tid; u < 2048; u += 256) {
                const int b = u >> 8, k4 = (u & 255) * 4;
                *(float4*)(hs + 8192 + swz(u * 4)) =
                    *(const float4*)(h2seq + ((size_t)b * TT + (it - 2)) * HH + k4);
            }
        } else {
            const float4 z4 = {0.f, 0.f, 0.f, 0.f};
#pragma unroll
            for (int u = tid; u < 2048; u += 256)
                *(float4*)(hs + 8192 + swz(u * 4)) = z4;
        }
        __syncthreads();

        // ---- dot phase: 2 batch-groups of 4, weights in registers
        float qv[2][9];
        const int kb = ln * 16;
#pragma unroll
        for (int g = 0; g < 2; ++g) {
            float p[9][4];
#pragma unroll
            for (int r = 0; r < 9; ++r)
#pragma unroll
                for (int bb = 0; bb < 4; ++bb) p[r][bb] = breg[r];
#pragma unroll
            for (int bb = 0; bb < 4; ++bb) {
                const int base = (g * 4 + bb) * 1024 + kb;
                if (n1 > 0) {
#pragma unroll
                    for (int j = 0; j < 4; ++j) {
                        const float4 x = *(const float4*)(hs + swz(base + j * 4));
#pragma unroll
                        for (int r = 0; r < 9; ++r) {
                            if (r < n1) {
                                p[r][bb] = fmaf(wr[r][j].x, x.x, p[r][bb]);
                                p[r][bb] = fmaf(wr[r][j].y, x.y, p[r][bb]);
                                p[r][bb] = fmaf(wr[r][j].z, x.z, p[r][bb]);
                                p[r][bb] = fmaf(wr[r][j].w, x.w, p[r][bb]);
                            }
                        }
                    }
                }
                if (n1 < 9) {
#pragma unroll
                    for (int j = 0; j < 4; ++j) {
                        const float4 x = *(const float4*)(hs + 8192 + swz(base + j * 4));
#pragma unroll
                        for (int r = 0; r < 9; ++r) {
                            if (r >= n1) {
                                p[r][bb] = fmaf(wr[r][j].x, x.x, p[r][bb]);
                                p[r][bb] = fmaf(wr[r][j].y, x.y, p[r][bb]);
                                p[r][bb] = fmaf(wr[r][j].z, x.z, p[r][bb]);
                                p[r][bb] = fmaf(wr[r][j].w, x.w, p[r][bb]);
                            }
                        }
                    }
                }
            }
            // reduce: intra-oct butterfly, select batch (ln&3), cross-oct sum
#pragma unroll
            for (int r = 0; r < 9; ++r) {
#pragma unroll
                for (int bb = 0; bb < 4; ++bb) {
                    p[r][bb] += __shfl_xor(p[r][bb], 1);
                    p[r][bb] += __shfl_xor(p[r][bb], 2);
                    p[r][bb] += __shfl_xor(p[r][bb], 4);
                }
                const float q0 = (ln & 1) ? p[r][1] : p[r][0];
                const float q1 = (ln & 1) ? p[r][3] : p[r][2];
                float q = (ln & 2) ? q1 : q0;
                q += __shfl_xor(q, 8);
                q += __shfl_xor(q, 16);
                q += __shfl_xor(q, 32);
                qv[g][r] = q;         // lane ln holds batch (g*4 + (ln&3))
            }
        }
        __syncthreads();              // all hs reads complete -> safe to alias
        if (ln < 4) {
#pragma unroll
            for (int g = 0; g < 2; ++g)
#pragma unroll
                for (int r = 0; r < 9; ++r)
                    ghb[(r0 + r) * 8 + g * 4 + ln] = qv[g][r];
        }
        __syncthreads();

        // ---- gate phase (wave 0); biases already inside ghb values
        if (tid < 32) {
            if (it < TT) {
                const int b2 = tid >> 2, cl = tid & 3, c = c0 + cl;
                const float hr = ghb[(cl * 3 + 0) * 8 + b2];
                const float hz = ghb[(cl * 3 + 1) * 8 + b2];
                const float hn = ghb[(cl * 3 + 2) * 8 + b2];
                const float rg = sigmf(xr + hr);
                const float zg = sigmf(xz + hz);
                const float ng = tanhf(xn + rg * hn);
                hreg = (1.f - zg) * ng + zg * hreg;
                h1buf[(it & 1) * (BB * HH) + b2 * HH + c] = hreg;
            }
        } else if (tid < 64) {
            if (it >= 1) {
                const int t2 = tid - 32, b2 = t2 >> 2, cl = t2 & 3, c = c0 + cl;
                const int s = it - 1;
                const float xr1 = ghb[(12 + cl * 3 + 0) * 8 + b2];
                const float xz1 = ghb[(12 + cl * 3 + 1) * 8 + b2];
                const float xn1 = ghb[(12 + cl * 3 + 2) * 8 + b2];
                const float hr1 = ghb[(24 + cl * 3 + 0) * 8 + b2];
                const float hz1 = ghb[(24 + cl * 3 + 1) * 8 + b2];
                const float hn1 = ghb[(24 + cl * 3 + 2) * 8 + b2];
                const float rg = sigmf(xr1 + hr1);
                const float zg = sigmf(xz1 + hz1);
                const float ng = tanhf(xn1 + rg * hn1);
                hreg = (1.f - zg) * ng + zg * hreg;
                h2seq[((size_t)b2 * TT + s) * HH + c] = hreg;
            }
        }

        // ---- grid barrier (monotonic counter, release/acquire) — proven
        __syncthreads();
        if (tid == 0) {
            __threadfence();  // release: flush so writes reach device scope
            __hip_atomic_fetch_add(bar, 1u, __ATOMIC_RELAXED, __HIP_MEMORY_SCOPE_AGENT);
            const unsigned target = (unsigned)NBLK2 * (unsigned)(it + 1);
            while (__hip_atomic_load(bar, __ATOMIC_RELAXED, __HIP_MEMORY_SCOPE_AGENT) < target) {
                __builtin_amdgcn_s_sleep(2);
            }
            __threadfence();  // acquire: invalidate caches before reading peers' h
        }
        __syncthreads();
    }
}

// ------------------------------------------------- K3: head GEMM
__global__ __launch_bounds__(256) void k_head(const float* __restrict__ h2,
                                              const float* __restrict__ fc_w,
                                              const float* __restrict__ fc_b,
                                              float* __restrict__ out) {
    __shared__ float As[16][136];
    __shared__ float Bs[16][136];
    const int tid = threadIdx.x;
    const int tx = tid & 15, ty = tid >> 4;
    const int m0 = blockIdx.x * 128;  // bt
    const int n0 = blockIdx.y * 128;  // vocab
    const int lrow = tid >> 1;        // 0..127
    const int lk   = (tid & 1) * 8;   // 0 or 8
    const float* aptr = h2   + (size_t)(m0 + lrow) * HH + lk;
    const float* bptr = fc_w + (size_t)(n0 + lrow) * HH + lk;

    float acc[8][8] = {};
    const int rbase = ty * 8, cbase = tx * 8;

    for (int k0 = 0; k0 < HH; k0 += 16) {
        const float4 a0 = *(const float4*)(aptr + k0);
        const float4 a1 = *(const float4*)(aptr + k0 + 4);
        const float4 b0 = *(const float4*)(bptr + k0);
        const float4 b1 = *(const float4*)(bptr + k0 + 4);
        As[lk + 0][lrow] = a0.x; As[lk + 1][lrow] = a0.y;
        As[lk + 2][lrow] = a0.z; As[lk + 3][lrow] = a0.w;
        As[lk + 4][lrow] = a1.x; As[lk + 5][lrow] = a1.y;
        As[lk + 6][lrow] = a1.z; As[lk + 7][lrow] = a1.w;
        Bs[lk + 0][lrow] = b0.x; Bs[lk + 1][lrow] = b0.y;
        Bs[lk + 2][lrow] = b0.z; Bs[lk + 3][lrow] = b0.w;
        Bs[lk + 4][lrow] = b1.x; Bs[lk + 5][lrow] = b1.y;
        Bs[lk + 6][lrow] = b1.z; Bs[lk + 7][lrow] = b1.w;
        __syncthreads();
#pragma unroll
        for (int k = 0; k < 16; ++k) {
            const float4 av0 = *(const float4*)&As[k][rbase];
            const float4 av1 = *(const float4*)&As[k][rbase + 4];
            const float4 bv0 = *(const float4*)&Bs[k][cbase];
            const float4 bv1 = *(const float4*)&Bs[k][cbase + 4];
            const float a[8] = {av0.x, av0.y, av0.z, av0.w, av1.x, av1.y, av1.z, av1.w};
            const float b[8] = {bv0.x, bv0.y, bv0.z, bv0.w, bv1.x, bv1.y, bv1.z, bv1.w};
#pragma unroll
            for (int i = 0; i < 8; ++i)
#pragma unroll
                for (int j = 0; j < 8; ++j)
                    acc[i][j] = fmaf(a[i], b[j], acc[i][j]);
        }
        __syncthreads();
    }
#pragma unroll
    for (int i = 0; i < 8; ++i) {
        const size_t r = (size_t)(m0 + rbase + i) * VV;
#pragma unroll
        for (int j = 0; j < 8; j += 4) {
            const int c = n0 + cbase + j;
            float4 o;
            o.x = acc[i][j + 0] + fc_b[c + 0];
            o.y = acc[i][j + 1] + fc_b[c + 1];
            o.z = acc[i][j + 2] + fc_b[c + 2];
            o.w = acc[i][j + 3] + fc_b[c + 3];
            *(float4*)(out + r + c) = o;
        }
    }
}

// ----------------------------------------------------------------- launch
extern "C" void kernel_launch(void* const* d_in, const int* in_sizes, int n_in,
                              void* d_out, int out_size, void* d_ws, size_t ws_size,
                              hipStream_t stream) {
    (void)in_sizes; (void)n_in; (void)out_size; (void)ws_size;
    const int*   xin   = (const int*)d_in[0];
    const float* emb   = (const float*)d_in[1];
    const float* w_ih0 = (const float*)d_in[2];
    const float* w_hh0 = (const float*)d_in[3];
    const float* b_ih0 = (const float*)d_in[4];
    const float* b_hh0 = (const float*)d_in[5];
    const float* w_ih1 = (const float*)d_in[6];
    const float* w_hh1 = (const float*)d_in[7];
    const float* b_ih1 = (const float*)d_in[8];
    const float* b_hh1 = (const float*)d_in[9];
    const float* fc_w  = (const float*)d_in[10];
    const float* fc_b  = (const float*)d_in[11];
    float* out = (float*)d_out;

    char* ws = (char*)d_ws;
    float*    gx0   = (float*)(ws + GX0_OFF);
    float*    h1buf = (float*)(ws + H1_OFF);
    float*    h2seq = (float*)(ws + H2_OFF);
    unsigned* bar   = (unsigned*)(ws + BAR_OFF);
    int*      xd    = (int*)(ws + XD_OFF);

    hipLaunchKernelGGL(k_init, dim3(1), dim3(1024), 0, stream, xin, xd, h1buf, bar);
    hipLaunchKernelGGL(k_gx0, dim3(48, 64), dim3(256), 0, stream,
                       emb, w_ih0, b_ih0, xd, gx0);
    hipLaunchKernelGGL(k_gru, dim3(NBLK2), dim3(256), 0, stream,
                       gx0, w_hh0, b_hh0, w_ih1, b_ih1, w_hh1, b_hh1,
                       h1buf, h2seq, bar);
    hipLaunchKernelGGL(k_head, dim3(32, 250), dim3(256), 0, stream,
                       h2seq, fc_w, fc_b, out);
}